// Round 3
// baseline (2214.097 us; speedup 1.0000x reference)
//
#include <hip/hip_runtime.h>
#include <hip/hip_bf16.h>

#define N_NODES 100000
#define N_EDGES 3200000
#define D 64
#define NEG_SLOPE 0.01f

#define B_SHIFT 9                          // bucket = 512 nodes
#define NB ((N_NODES + 511) >> B_SHIFT)    // 196 buckets
#define NBLK ((N_NODES + 255) / 256)       // 391 scan blocks
#define T_EDGES 16384                      // edges per binning block
#define NBIN ((N_EDGES + T_EDGES - 1) / T_EDGES)  // 196 binning blocks

// ---------------- degree histogram ----------------
__global__ __launch_bounds__(256) void hist_k(const int* __restrict__ dst, int* __restrict__ degi) {
    int e = blockIdx.x * 256 + threadIdx.x;
    if (e < N_EDGES) atomicAdd(&degi[dst[e]], 1);
}

// ---------------- ordered exclusive scan (3 kernels) ----------------
__global__ __launch_bounds__(256) void scan_blk(const int* __restrict__ degi, int* __restrict__ offs,
                                                int* __restrict__ bsum) {
    __shared__ int wsum[4];
    int t = threadIdx.x;
    int i = blockIdx.x * 256 + t;
    int lane = t & 63, w = t >> 6;
    int d = (i < N_NODES) ? degi[i] : 0;
    int incl = d;
    #pragma unroll
    for (int o = 1; o < 64; o <<= 1) {
        int v = __shfl_up(incl, o, 64);
        if (lane >= o) incl += v;
    }
    if (lane == 63) wsum[w] = incl;
    __syncthreads();
    int woff = 0;
    for (int k = 0; k < w; ++k) woff += wsum[k];
    if (i < N_NODES) offs[i] = woff + incl - d;
    if (t == 255) bsum[blockIdx.x] = woff + incl;
}

__global__ __launch_bounds__(512) void scan_top(int* __restrict__ bsum) {
    __shared__ int wsum[8];
    int t = threadIdx.x;
    int lane = t & 63, w = t >> 6;
    int v = (t < NBLK) ? bsum[t] : 0;
    int incl = v;
    #pragma unroll
    for (int o = 1; o < 64; o <<= 1) {
        int u = __shfl_up(incl, o, 64);
        if (lane >= o) incl += u;
    }
    if (lane == 63) wsum[w] = incl;
    __syncthreads();
    int woff = 0;
    for (int k = 0; k < w; ++k) woff += wsum[k];
    if (t < NBLK) bsum[t] = woff + incl - v;
}

__global__ __launch_bounds__(256) void scan_add(const int* __restrict__ degi, int* __restrict__ offs,
                                                const int* __restrict__ bsum, float* __restrict__ rsd) {
    int i = blockIdx.x * 256 + threadIdx.x;
    if (i < N_NODES) {
        offs[i] += bsum[i >> 8];
        int d = degi[i];
        rsd[i] = rsqrtf((float)(d > 0 ? d : 1));
    }
}

// ---------------- two-level edge placement ----------------
// coarse: per-block LDS histogram -> ONE global atomic per (block,bucket), then
// place pairs in per-block contiguous chunks inside each bucket region.
__global__ __launch_bounds__(256) void bucket_k(const int* __restrict__ src, const int* __restrict__ dst,
                                                const int* __restrict__ offs, int* __restrict__ bcnt,
                                                int2* __restrict__ pairs) {
    __shared__ int hist[NB];
    __shared__ int cnt2[NB];
    __shared__ int baseL[NB];
    __shared__ int gbase[NB];
    int tid = threadIdx.x;
    for (int b = tid; b < NB; b += 256) { hist[b] = 0; cnt2[b] = 0; }
    __syncthreads();
    int e0 = blockIdx.x * T_EDGES;
    int e1 = min(e0 + T_EDGES, N_EDGES);
    for (int e = e0 + tid; e < e1; e += 256) atomicAdd(&hist[dst[e] >> B_SHIFT], 1);
    __syncthreads();
    for (int b = tid; b < NB; b += 256) {
        baseL[b] = atomicAdd(&bcnt[b], hist[b]);   // 38K global atomics total, spread
        gbase[b] = offs[b << B_SHIFT];             // bucket's CSR start
    }
    __syncthreads();
    for (int e = e0 + tid; e < e1; e += 256) {
        int dv = dst[e];
        int b = dv >> B_SHIFT;
        int p = atomicAdd(&cnt2[b], 1);
        pairs[(size_t)gbase[b] + baseL[b] + p] = make_int2(src[e], dv);
    }
}

// fine: one block per bucket; 512 LDS counters; scatter into the bucket's
// contiguous ~64 KB csr window (L2-hot lines).
__global__ __launch_bounds__(512) void fine_k(const int2* __restrict__ pairs, const int* __restrict__ offs,
                                              int* __restrict__ csr_src) {
    __shared__ int cnt[512];
    __shared__ int offl[512];
    int b = blockIdx.x, t = threadIdx.x;
    int n0 = b << B_SHIFT;
    int n = n0 + t;
    cnt[t] = 0;
    offl[t] = (n < N_NODES) ? offs[n] : N_EDGES;
    __syncthreads();
    int start = offl[0];
    int nend = (b + 1) << B_SHIFT;
    int end = (nend < N_NODES) ? offs[nend] : N_EDGES;
    for (int e = start + t; e < end; e += 512) {
        int2 pr = pairs[e];
        int li = pr.y & 511;
        int p = atomicAdd(&cnt[li], 1);
        csr_src[offl[li] + p] = pr.x;
    }
}

// ---------------- per-layer: weighted neighbor sum ----------------
// wave per node; lane = (edge-slot g in 0..3, feature-quad q in 0..15):
// 4 edges in flight per load instr, float4 per lane (1 KB/instr), xor-shuffle reduce.
__global__ __launch_bounds__(256) void agg_k(const float* __restrict__ in, int stride4,
                                             const float* __restrict__ rsd,
                                             const int* __restrict__ offs, const int* __restrict__ degi,
                                             const int* __restrict__ csr_src, float* __restrict__ s) {
    int node = blockIdx.x * 4 + (threadIdx.x >> 6);
    if (node >= N_NODES) return;
    int lane = threadIdx.x & 63;
    int g = lane >> 4;
    int q = lane & 15;
    int start = offs[node];
    int deg = degi[node];
    const float4* in4 = (const float4*)in;
    float4 acc = {0.f, 0.f, 0.f, 0.f};
    for (int j = 0; j < deg; j += 4) {
        int e = j + g;
        bool v = e < deg;
        int sj = csr_src[start + (v ? e : 0)];
        float r = v ? rsd[sj] : 0.f;
        float4 xv = in4[(size_t)sj * stride4 + q];
        acc.x += r * xv.x;
        acc.y += r * xv.y;
        acc.z += r * xv.z;
        acc.w += r * xv.w;
    }
    #pragma unroll
    for (int off = 16; off < 64; off <<= 1) {
        acc.x += __shfl_xor(acc.x, off, 64);
        acc.y += __shfl_xor(acc.y, off, 64);
        acc.z += __shfl_xor(acc.z, off, 64);
        acc.w += __shfl_xor(acc.w, off, 64);
    }
    if (g == 0) {
        float rn = rsd[node];
        float4 r;
        r.x = rn * acc.x; r.y = rn * acc.y; r.z = rn * acc.z; r.w = rn * acc.w;
        ((float4*)s)[node * 16 + q] = r;
    }
}

// ---------------- per-layer: combine + GEMM ----------------
// block = 64 nodes; wave handles 16 nodes (4 i-slots x 4 m); W rows broadcast from
// LDS (same-address, free), a/b broadcast per 16-lane group -> 16 b128/node.
__global__ __launch_bounds__(256) void comb_k(const float* __restrict__ in, int stride,
                                              const float* __restrict__ s,
                                              const float* __restrict__ W1, const float* __restrict__ W2,
                                              float* __restrict__ out, int act) {
    __shared__ float W1s[D * D];
    __shared__ float W2s[D * D];
    __shared__ float aL[64][72];   // +8 pad: m=0..3 rows land on distinct bank quads
    __shared__ float bL[64][72];
    int tid = threadIdx.x;
    {
        const float4* w1v = (const float4*)W1;
        const float4* w2v = (const float4*)W2;
        float4* w1s = (float4*)W1s;
        float4* w2s = (float4*)W2s;
        for (int t = tid; t < D * D / 4; t += 256) { w1s[t] = w1v[t]; w2s[t] = w2v[t]; }
    }
    int n0 = blockIdx.x * 64;
    for (int idx = tid; idx < 64 * 16; idx += 256) {
        int nl = idx >> 4, qq = idx & 15;
        int n = n0 + nl;
        float4 xv = {0.f, 0.f, 0.f, 0.f}, sp = xv;
        if (n < N_NODES) {
            xv = *(const float4*)&in[(size_t)n * stride + 4 * qq];
            sp = *(const float4*)&s[(size_t)n * D + 4 * qq];
        }
        float4 a4, b4;
        a4.x = xv.x + sp.x; a4.y = xv.y + sp.y; a4.z = xv.z + sp.z; a4.w = xv.w + sp.w;
        b4.x = xv.x * sp.x; b4.y = xv.y * sp.y; b4.z = xv.z * sp.z; b4.w = xv.w * sp.w;
        *(float4*)&aL[nl][4 * qq] = a4;
        *(float4*)&bL[nl][4 * qq] = b4;
    }
    __syncthreads();
    int w = tid >> 6, l = tid & 63, m = l >> 4, q = l & 15;
    float4 acc[4];
    #pragma unroll
    for (int i = 0; i < 4; ++i) acc[i] = {0.f, 0.f, 0.f, 0.f};
    #pragma unroll
    for (int kk = 0; kk < 16; ++kk) {
        float4 a4[4], b4[4];
        #pragma unroll
        for (int i = 0; i < 4; ++i) {
            int nl = w * 16 + i * 4 + m;
            a4[i] = *(const float4*)&aL[nl][kk * 4];
            b4[i] = *(const float4*)&bL[nl][kk * 4];
        }
        #pragma unroll
        for (int j = 0; j < 4; ++j) {
            int k = kk * 4 + j;
            float4 w1 = *(const float4*)&W1s[k * D + q * 4];
            float4 w2 = *(const float4*)&W2s[k * D + q * 4];
            #pragma unroll
            for (int i = 0; i < 4; ++i) {
                float aj = (j == 0) ? a4[i].x : (j == 1) ? a4[i].y : (j == 2) ? a4[i].z : a4[i].w;
                float bj = (j == 0) ? b4[i].x : (j == 1) ? b4[i].y : (j == 2) ? b4[i].z : b4[i].w;
                acc[i].x += aj * w1.x + bj * w2.x;
                acc[i].y += aj * w1.y + bj * w2.y;
                acc[i].z += aj * w1.z + bj * w2.z;
                acc[i].w += aj * w1.w + bj * w2.w;
            }
        }
    }
    #pragma unroll
    for (int i = 0; i < 4; ++i) {
        int n = n0 + w * 16 + i * 4 + m;
        if (n < N_NODES) {
            float4 r = acc[i];
            if (act) {
                r.x = r.x >= 0.f ? r.x : NEG_SLOPE * r.x;
                r.y = r.y >= 0.f ? r.y : NEG_SLOPE * r.y;
                r.z = r.z >= 0.f ? r.z : NEG_SLOPE * r.z;
                r.w = r.w >= 0.f ? r.w : NEG_SLOPE * r.w;
            }
            *(float4*)&out[(size_t)n * 192 + q * 4] = r;
        }
    }
}

extern "C" void kernel_launch(void* const* d_in, const int* in_sizes, int n_in,
                              void* d_out, int out_size, void* d_ws, size_t ws_size,
                              hipStream_t stream) {
    const float* x   = (const float*)d_in[0];
    const float* W1a = (const float*)d_in[1];
    const float* W2a = (const float*)d_in[2];
    const float* W1b = (const float*)d_in[3];
    const float* W2b = (const float*)d_in[4];
    const int*   src = (const int*)d_in[5];
    const int*   dst = (const int*)d_in[6];
    float* out = (float*)d_out;

    // workspace layout (~66 MB)
    int*   degi    = (int*)d_ws;                    // N
    int*   offs    = degi + N_NODES;                // N
    float* rsd     = (float*)(offs + N_NODES);      // N
    int*   bsum    = (int*)(rsd + N_NODES);         // NBLK pad 512
    int*   bcnt    = bsum + 512;                    // NB pad 1024
    int*   csr_src = bcnt + 1024;                   // E
    int2*  pairs   = (int2*)(csr_src + N_EDGES);    // E
    float* s       = (float*)(pairs + N_EDGES);     // N*D

    hipMemsetAsync(degi, 0, N_NODES * sizeof(int), stream);
    hipMemsetAsync(bcnt, 0, 1024 * sizeof(int), stream);

    int eb = (N_EDGES + 255) / 256;
    hist_k<<<eb, 256, 0, stream>>>(dst, degi);
    scan_blk<<<NBLK, 256, 0, stream>>>(degi, offs, bsum);
    scan_top<<<1, 512, 0, stream>>>(bsum);
    scan_add<<<NBLK, 256, 0, stream>>>(degi, offs, bsum, rsd);
    bucket_k<<<NBIN, 256, 0, stream>>>(src, dst, offs, bcnt, pairs);
    fine_k<<<NB, 512, 0, stream>>>(pairs, offs, csr_src);

    int ab = (N_NODES + 3) / 4;          // wave per node
    int cbg = (N_NODES + 63) / 64;       // 1563

    // layer 1: h1 = lrelu(conv(x, W1a, W2a)) -> out cols [0,64)
    agg_k<<<ab, 256, 0, stream>>>(x, 16, rsd, offs, degi, csr_src, s);
    comb_k<<<cbg, 256, 0, stream>>>(x, D, s, W1a, W2a, out + 0, 1);
    // layer 2: h2 = lrelu(conv(h1, W1b, W2b)) -> out cols [64,128)
    agg_k<<<ab, 256, 0, stream>>>(out + 0, 48, rsd, offs, degi, csr_src, s);
    comb_k<<<cbg, 256, 0, stream>>>(out + 0, 192, s, W1b, W2b, out + 64, 1);
    // layer 3: h3 = conv(h2, W1b, W2b) (no act) -> out cols [128,192)
    agg_k<<<ab, 256, 0, stream>>>(out + 64, 48, rsd, offs, degi, csr_src, s);
    comb_k<<<cbg, 256, 0, stream>>>(out + 64, 192, s, W1b, W2b, out + 128, 0);
}

// Round 4
// 845.263 us; speedup vs baseline: 2.6194x; 2.6194x over previous
//
#include <hip/hip_runtime.h>
#include <hip/hip_bf16.h>

#define N_NODES 100000
#define N_EDGES 3200000
#define D 64
#define NEG_SLOPE 0.01f

#define B_SHIFT 9                          // bucket = 512 nodes
#define NB ((N_NODES + 511) >> B_SHIFT)    // 196 buckets
#define NBLK ((N_NODES + 255) / 256)       // 391 scan blocks
#define T_EDGES 16384                      // edges per binning block
#define NBIN ((N_EDGES + T_EDGES - 1) / T_EDGES)  // 196 binning blocks

// ---------------- degree histogram ----------------
__global__ __launch_bounds__(256) void hist_k(const int* __restrict__ dst, int* __restrict__ degi) {
    int e = blockIdx.x * 256 + threadIdx.x;
    if (e < N_EDGES) atomicAdd(&degi[dst[e]], 1);
}

// ---------------- ordered exclusive scan (3 kernels) ----------------
__global__ __launch_bounds__(256) void scan_blk(const int* __restrict__ degi, int* __restrict__ offs,
                                                int* __restrict__ bsum) {
    __shared__ int wsum[4];
    int t = threadIdx.x;
    int i = blockIdx.x * 256 + t;
    int lane = t & 63, w = t >> 6;
    int d = (i < N_NODES) ? degi[i] : 0;
    int incl = d;
    #pragma unroll
    for (int o = 1; o < 64; o <<= 1) {
        int v = __shfl_up(incl, o, 64);
        if (lane >= o) incl += v;
    }
    if (lane == 63) wsum[w] = incl;
    __syncthreads();
    int woff = 0;
    for (int k = 0; k < w; ++k) woff += wsum[k];
    if (i < N_NODES) offs[i] = woff + incl - d;
    if (t == 255) bsum[blockIdx.x] = woff + incl;
}

__global__ __launch_bounds__(512) void scan_top(int* __restrict__ bsum) {
    __shared__ int wsum[8];
    int t = threadIdx.x;
    int lane = t & 63, w = t >> 6;
    int v = (t < NBLK) ? bsum[t] : 0;
    int incl = v;
    #pragma unroll
    for (int o = 1; o < 64; o <<= 1) {
        int u = __shfl_up(incl, o, 64);
        if (lane >= o) incl += u;
    }
    if (lane == 63) wsum[w] = incl;
    __syncthreads();
    int woff = 0;
    for (int k = 0; k < w; ++k) woff += wsum[k];
    if (t < NBLK) bsum[t] = woff + incl - v;
}

__global__ __launch_bounds__(256) void scan_add(const int* __restrict__ degi, int* __restrict__ offs,
                                                const int* __restrict__ bsum, float* __restrict__ rsd) {
    int i = blockIdx.x * 256 + threadIdx.x;
    if (i < N_NODES) {
        offs[i] += bsum[i >> 8];
        int d = degi[i];
        rsd[i] = rsqrtf((float)(d > 0 ? d : 1));
    }
}

// ---------------- two-level edge placement ----------------
__global__ __launch_bounds__(256) void bucket_k(const int* __restrict__ src, const int* __restrict__ dst,
                                                const int* __restrict__ offs, int* __restrict__ bcnt,
                                                int2* __restrict__ pairs) {
    __shared__ int hist[NB];
    __shared__ int cnt2[NB];
    __shared__ int baseL[NB];
    __shared__ int gbase[NB];
    int tid = threadIdx.x;
    for (int b = tid; b < NB; b += 256) { hist[b] = 0; cnt2[b] = 0; }
    __syncthreads();
    int e0 = blockIdx.x * T_EDGES;
    int e1 = min(e0 + T_EDGES, N_EDGES);
    for (int e = e0 + tid; e < e1; e += 256) atomicAdd(&hist[dst[e] >> B_SHIFT], 1);
    __syncthreads();
    for (int b = tid; b < NB; b += 256) {
        baseL[b] = atomicAdd(&bcnt[b], hist[b]);
        gbase[b] = offs[b << B_SHIFT];
    }
    __syncthreads();
    for (int e = e0 + tid; e < e1; e += 256) {
        int dv = dst[e];
        int b = dv >> B_SHIFT;
        int p = atomicAdd(&cnt2[b], 1);
        pairs[(size_t)gbase[b] + baseL[b] + p] = make_int2(src[e], dv);
    }
}

// fine: one block per bucket; 512 LDS counters; scatter into the bucket's
// contiguous ~64 KB csr window (L2-hot lines).
__global__ __launch_bounds__(512) void fine_k(const int2* __restrict__ pairs, const int* __restrict__ offs,
                                              int* __restrict__ csr_src) {
    __shared__ int cnt[512];
    __shared__ int offl[512];
    int b = blockIdx.x, t = threadIdx.x;
    int n0 = b << B_SHIFT;
    int n = n0 + t;
    cnt[t] = 0;
    offl[t] = (n < N_NODES) ? offs[n] : N_EDGES;
    __syncthreads();
    int start = offl[0];
    int nend = (b + 1) << B_SHIFT;
    int end = (nend < N_NODES) ? offs[nend] : N_EDGES;
    for (int e = start + t; e < end; e += 512) {
        int2 pr = pairs[e];
        int li = pr.y & 511;
        int p = atomicAdd(&cnt[li], 1);
        csr_src[offl[li] + p] = pr.x;
    }
}

// ---------------- per-layer: weighted neighbor sum ----------------
__global__ __launch_bounds__(256) void agg_k(const float* __restrict__ in, int stride4,
                                             const float* __restrict__ rsd,
                                             const int* __restrict__ offs, const int* __restrict__ degi,
                                             const int* __restrict__ csr_src, float* __restrict__ s) {
    int node = blockIdx.x * 4 + (threadIdx.x >> 6);
    if (node >= N_NODES) return;
    int lane = threadIdx.x & 63;
    int g = lane >> 4;
    int q = lane & 15;
    int start = offs[node];
    int deg = degi[node];
    const float4* in4 = (const float4*)in;
    float4 acc = {0.f, 0.f, 0.f, 0.f};
    for (int j = 0; j < deg; j += 4) {
        int e = j + g;
        bool v = e < deg;
        int sj = csr_src[start + (v ? e : 0)];
        float r = v ? rsd[sj] : 0.f;
        float4 xv = in4[(size_t)sj * stride4 + q];
        acc.x += r * xv.x;
        acc.y += r * xv.y;
        acc.z += r * xv.z;
        acc.w += r * xv.w;
    }
    #pragma unroll
    for (int off = 16; off < 64; off <<= 1) {
        acc.x += __shfl_xor(acc.x, off, 64);
        acc.y += __shfl_xor(acc.y, off, 64);
        acc.z += __shfl_xor(acc.z, off, 64);
        acc.w += __shfl_xor(acc.w, off, 64);
    }
    if (g == 0) {
        float rn = rsd[node];
        float4 r;
        r.x = rn * acc.x; r.y = rn * acc.y; r.z = rn * acc.z; r.w = rn * acc.w;
        ((float4*)s)[node * 16 + q] = r;
    }
}

// ---------------- per-layer: combine + GEMM (round-1 proven version) ----------------
__global__ __launch_bounds__(256) void comb_k(const float* __restrict__ in, int stride,
                                              const float* __restrict__ s,
                                              const float* __restrict__ W1, const float* __restrict__ W2,
                                              float* __restrict__ out, int act) {
    __shared__ float W1s[D * D];
    __shared__ float W2s[D * D];
    __shared__ float aL[4][4][D];   // [wave][m][k]
    __shared__ float bL[4][4][D];
    int tid = threadIdx.x;
    {
        const float4* w1v = (const float4*)W1;
        const float4* w2v = (const float4*)W2;
        float4* w1s = (float4*)W1s;
        float4* w2s = (float4*)W2s;
        for (int t = tid; t < D * D / 4; t += 256) { w1s[t] = w1v[t]; w2s[t] = w2v[t]; }
    }
    int w = tid >> 6;
    int l = tid & 63;
    int m = l >> 4;
    int cb = (l & 15) * 4;
    __syncthreads();
    for (int it = 0; it < 2; ++it) {
        int n0 = blockIdx.x * 32 + it * 16 + w * 4;
        #pragma unroll
        for (int mm = 0; mm < 4; ++mm) {
            float xv = in[(size_t)(n0 + mm) * stride + l];
            float sp = s[(size_t)(n0 + mm) * D + l];
            aL[w][mm][l] = xv + sp;
            bL[w][mm][l] = sp * xv;
        }
        __syncthreads();
        float acc0 = 0.f, acc1 = 0.f, acc2 = 0.f, acc3 = 0.f;
        const float4* aV = (const float4*)&aL[w][m][0];
        const float4* bV = (const float4*)&bL[w][m][0];
        #pragma unroll
        for (int kk = 0; kk < 16; ++kk) {
            float4 a4 = aV[kk];
            float4 b4 = bV[kk];
            #pragma unroll
            for (int j = 0; j < 4; ++j) {
                int k = kk * 4 + j;
                float aj = (j == 0) ? a4.x : (j == 1) ? a4.y : (j == 2) ? a4.z : a4.w;
                float bj = (j == 0) ? b4.x : (j == 1) ? b4.y : (j == 2) ? b4.z : b4.w;
                float4 w1 = *(const float4*)&W1s[k * D + cb];
                float4 w2 = *(const float4*)&W2s[k * D + cb];
                acc0 += aj * w1.x + bj * w2.x;
                acc1 += aj * w1.y + bj * w2.y;
                acc2 += aj * w1.z + bj * w2.z;
                acc3 += aj * w1.w + bj * w2.w;
            }
        }
        int n = n0 + m;
        float4 r;
        r.x = acc0; r.y = acc1; r.z = acc2; r.w = acc3;
        if (act) {
            r.x = r.x >= 0.f ? r.x : NEG_SLOPE * r.x;
            r.y = r.y >= 0.f ? r.y : NEG_SLOPE * r.y;
            r.z = r.z >= 0.f ? r.z : NEG_SLOPE * r.z;
            r.w = r.w >= 0.f ? r.w : NEG_SLOPE * r.w;
        }
        *(float4*)&out[(size_t)n * 192 + cb] = r;
        __syncthreads();
    }
}

extern "C" void kernel_launch(void* const* d_in, const int* in_sizes, int n_in,
                              void* d_out, int out_size, void* d_ws, size_t ws_size,
                              hipStream_t stream) {
    const float* x   = (const float*)d_in[0];
    const float* W1a = (const float*)d_in[1];
    const float* W2a = (const float*)d_in[2];
    const float* W1b = (const float*)d_in[3];
    const float* W2b = (const float*)d_in[4];
    const int*   src = (const int*)d_in[5];
    const int*   dst = (const int*)d_in[6];
    float* out = (float*)d_out;

    // workspace layout (~66 MB)
    int*   degi    = (int*)d_ws;                    // N
    int*   offs    = degi + N_NODES;                // N
    float* rsd     = (float*)(offs + N_NODES);      // N
    int*   bsum    = (int*)(rsd + N_NODES);         // NBLK pad 512
    int*   bcnt    = bsum + 512;                    // NB pad 1024
    int*   csr_src = bcnt + 1024;                   // E
    int2*  pairs   = (int2*)(csr_src + N_EDGES);    // E
    float* s       = (float*)(pairs + N_EDGES);     // N*D

    hipMemsetAsync(degi, 0, N_NODES * sizeof(int), stream);
    hipMemsetAsync(bcnt, 0, 1024 * sizeof(int), stream);

    int eb = (N_EDGES + 255) / 256;
    hist_k<<<eb, 256, 0, stream>>>(dst, degi);
    scan_blk<<<NBLK, 256, 0, stream>>>(degi, offs, bsum);
    scan_top<<<1, 512, 0, stream>>>(bsum);
    scan_add<<<NBLK, 256, 0, stream>>>(degi, offs, bsum, rsd);
    bucket_k<<<NBIN, 256, 0, stream>>>(src, dst, offs, bcnt, pairs);
    fine_k<<<NB, 512, 0, stream>>>(pairs, offs, csr_src);

    int ab = (N_NODES + 3) / 4;   // wave per node
    int cbg = N_NODES / 32;       // 3125, exact

    // layer 1: h1 = lrelu(conv(x, W1a, W2a)) -> out cols [0,64)
    agg_k<<<ab, 256, 0, stream>>>(x, 16, rsd, offs, degi, csr_src, s);
    comb_k<<<cbg, 256, 0, stream>>>(x, D, s, W1a, W2a, out + 0, 1);
    // layer 2: h2 = lrelu(conv(h1, W1b, W2b)) -> out cols [64,128)
    agg_k<<<ab, 256, 0, stream>>>(out + 0, 48, rsd, offs, degi, csr_src, s);
    comb_k<<<cbg, 256, 0, stream>>>(out + 0, 192, s, W1b, W2b, out + 64, 1);
    // layer 3: h3 = conv(h2, W1b, W2b) (no act) -> out cols [128,192)
    agg_k<<<ab, 256, 0, stream>>>(out + 64, 48, rsd, offs, degi, csr_src, s);
    comb_k<<<cbg, 256, 0, stream>>>(out + 64, 192, s, W1b, W2b, out + 128, 0);
}

// Round 5
// 734.705 us; speedup vs baseline: 3.0136x; 1.1505x over previous
//
#include <hip/hip_runtime.h>
#include <hip/hip_bf16.h>

#define N_NODES 100000
#define N_EDGES 3200000
#define D 64
#define NEG_SLOPE 0.01f

#define B_SHIFT 9                          // bucket = 512 nodes
#define NB ((N_NODES + 511) >> B_SHIFT)    // 196 buckets
#define T_EDGES 16384                      // edges per binning block
#define NBIN ((N_EDGES + T_EDGES - 1) / T_EDGES)  // 196 binning blocks

// ---------------- bucket histogram (196 counters, LDS-accumulated) ----------------
__global__ __launch_bounds__(256) void bhist_k(const int* __restrict__ dst, int* __restrict__ btot) {
    __shared__ int hist[NB];
    int tid = threadIdx.x;
    for (int b = tid; b < NB; b += 256) hist[b] = 0;
    __syncthreads();
    int e0 = blockIdx.x * T_EDGES;
    int e1 = min(e0 + T_EDGES, N_EDGES);
    for (int e = e0 + tid; e < e1; e += 256) atomicAdd(&hist[dst[e] >> B_SHIFT], 1);
    __syncthreads();
    for (int b = tid; b < NB; b += 256) {
        int h = hist[b];
        if (h) atomicAdd(&btot[b], h);
    }
}

// one-block exclusive scan over the 196 bucket totals -> bbase[0..NB], bbase[NB]=E
__global__ __launch_bounds__(256) void bscan_k(const int* __restrict__ btot, int* __restrict__ bbase) {
    __shared__ int wsum[4];
    int t = threadIdx.x;
    int lane = t & 63, w = t >> 6;
    int v = (t < NB) ? btot[t] : 0;
    int incl = v;
    #pragma unroll
    for (int o = 1; o < 64; o <<= 1) {
        int u = __shfl_up(incl, o, 64);
        if (lane >= o) incl += u;
    }
    if (lane == 63) wsum[w] = incl;
    __syncthreads();
    int woff = 0;
    for (int k = 0; k < w; ++k) woff += wsum[k];
    if (t < NB) bbase[t] = woff + incl - v;
    if (t == NB) bbase[NB] = N_EDGES;
}

// ---------------- coarse placement: per-block LDS histogram -> chunked append ----------------
__global__ __launch_bounds__(256) void bucket_k(const int* __restrict__ src, const int* __restrict__ dst,
                                                const int* __restrict__ bbase, int* __restrict__ bcnt2,
                                                int2* __restrict__ pairs) {
    __shared__ int hist[NB];
    __shared__ int cnt2[NB];
    __shared__ int baseL[NB];
    int tid = threadIdx.x;
    for (int b = tid; b < NB; b += 256) { hist[b] = 0; cnt2[b] = 0; }
    __syncthreads();
    int e0 = blockIdx.x * T_EDGES;
    int e1 = min(e0 + T_EDGES, N_EDGES);
    for (int e = e0 + tid; e < e1; e += 256) atomicAdd(&hist[dst[e] >> B_SHIFT], 1);
    __syncthreads();
    for (int b = tid; b < NB; b += 256) {
        int h = hist[b];
        int p = h ? atomicAdd(&bcnt2[b], h) : 0;
        baseL[b] = bbase[b] + p;          // this block's contiguous chunk in bucket b
    }
    __syncthreads();
    for (int e = e0 + tid; e < e1; e += 256) {
        int dv = dst[e];
        int b = dv >> B_SHIFT;
        int p = atomicAdd(&cnt2[b], 1);
        pairs[(size_t)baseL[b] + p] = make_int2(src[e], dv);
    }
}

// ---------------- fine: per-bucket degree count + scan + scatter ----------------
// one block per bucket (512 nodes). pairs window (~130 KB) is L2-hot; two passes.
// Writes degi/offs/rsd (contiguous) and csr_src (bucket-local ~64 KB window).
__global__ __launch_bounds__(512) void fine_k(const int2* __restrict__ pairs, const int* __restrict__ bbase,
                                              int* __restrict__ degi, int* __restrict__ offs,
                                              float* __restrict__ rsd, int* __restrict__ csr_src) {
    __shared__ int cnt[512];
    __shared__ int offl[512];
    __shared__ int wsum[8];
    int b = blockIdx.x, t = threadIdx.x;
    int start = bbase[b];
    int end = bbase[b + 1];
    cnt[t] = 0;
    __syncthreads();
    // pass 1: degree histogram for this bucket's 512 nodes
    for (int e = start + t; e < end; e += 512) atomicAdd(&cnt[pairs[e].y & 511], 1);
    __syncthreads();
    // 512-wide exclusive scan of cnt -> node offsets within the bucket window
    int d = cnt[t];
    int lane = t & 63, w = t >> 6;
    int incl = d;
    #pragma unroll
    for (int o = 1; o < 64; o <<= 1) {
        int u = __shfl_up(incl, o, 64);
        if (lane >= o) incl += u;
    }
    if (lane == 63) wsum[w] = incl;
    __syncthreads();
    int woff = 0;
    for (int k = 0; k < w; ++k) woff += wsum[k];
    int myoff = start + woff + incl - d;
    offl[t] = myoff;
    int n = (b << B_SHIFT) + t;
    if (n < N_NODES) {
        degi[n] = d;
        offs[n] = myoff;
        rsd[n] = rsqrtf((float)(d > 0 ? d : 1));
    }
    cnt[t] = 0;
    __syncthreads();
    // pass 2: scatter src ids into csr (all target lines L2-hot)
    for (int e = start + t; e < end; e += 512) {
        int2 pr = pairs[e];
        int li = pr.y & 511;
        int p = atomicAdd(&cnt[li], 1);
        csr_src[offl[li] + p] = pr.x;
    }
}

// ---------------- per-layer: weighted neighbor sum ----------------
// wave per node; lane = (edge-slot g in 0..3, feature-quad q in 0..15):
// 4 edges in flight per load instr, float4 per lane, xor-shuffle reduce.
__global__ __launch_bounds__(256) void agg_k(const float* __restrict__ in, int stride4,
                                             const float* __restrict__ rsd,
                                             const int* __restrict__ offs, const int* __restrict__ degi,
                                             const int* __restrict__ csr_src, float* __restrict__ s) {
    int node = blockIdx.x * 4 + (threadIdx.x >> 6);
    if (node >= N_NODES) return;
    int lane = threadIdx.x & 63;
    int g = lane >> 4;
    int q = lane & 15;
    int start = offs[node];
    int deg = degi[node];
    const float4* in4 = (const float4*)in;
    float4 acc = {0.f, 0.f, 0.f, 0.f};
    for (int j = 0; j < deg; j += 4) {
        int e = j + g;
        bool v = e < deg;
        int sj = csr_src[start + (v ? e : 0)];
        float r = v ? rsd[sj] : 0.f;
        float4 xv = in4[(size_t)sj * stride4 + q];
        acc.x += r * xv.x;
        acc.y += r * xv.y;
        acc.z += r * xv.z;
        acc.w += r * xv.w;
    }
    #pragma unroll
    for (int off = 16; off < 64; off <<= 1) {
        acc.x += __shfl_xor(acc.x, off, 64);
        acc.y += __shfl_xor(acc.y, off, 64);
        acc.z += __shfl_xor(acc.z, off, 64);
        acc.w += __shfl_xor(acc.w, off, 64);
    }
    if (g == 0) {
        float rn = rsd[node];
        float4 r;
        r.x = rn * acc.x; r.y = rn * acc.y; r.z = rn * acc.z; r.w = rn * acc.w;
        ((float4*)s)[node * 16 + q] = r;
    }
}

// ---------------- per-layer: combine + GEMM (round-1 proven version) ----------------
__global__ __launch_bounds__(256) void comb_k(const float* __restrict__ in, int stride,
                                              const float* __restrict__ s,
                                              const float* __restrict__ W1, const float* __restrict__ W2,
                                              float* __restrict__ out, int act) {
    __shared__ float W1s[D * D];
    __shared__ float W2s[D * D];
    __shared__ float aL[4][4][D];   // [wave][m][k]
    __shared__ float bL[4][4][D];
    int tid = threadIdx.x;
    {
        const float4* w1v = (const float4*)W1;
        const float4* w2v = (const float4*)W2;
        float4* w1s = (float4*)W1s;
        float4* w2s = (float4*)W2s;
        for (int t = tid; t < D * D / 4; t += 256) { w1s[t] = w1v[t]; w2s[t] = w2v[t]; }
    }
    int w = tid >> 6;
    int l = tid & 63;
    int m = l >> 4;
    int cb = (l & 15) * 4;
    __syncthreads();
    for (int it = 0; it < 2; ++it) {
        int n0 = blockIdx.x * 32 + it * 16 + w * 4;
        #pragma unroll
        for (int mm = 0; mm < 4; ++mm) {
            float xv = in[(size_t)(n0 + mm) * stride + l];
            float sp = s[(size_t)(n0 + mm) * D + l];
            aL[w][mm][l] = xv + sp;
            bL[w][mm][l] = sp * xv;
        }
        __syncthreads();
        float acc0 = 0.f, acc1 = 0.f, acc2 = 0.f, acc3 = 0.f;
        const float4* aV = (const float4*)&aL[w][m][0];
        const float4* bV = (const float4*)&bL[w][m][0];
        #pragma unroll
        for (int kk = 0; kk < 16; ++kk) {
            float4 a4 = aV[kk];
            float4 b4 = bV[kk];
            #pragma unroll
            for (int j = 0; j < 4; ++j) {
                int k = kk * 4 + j;
                float aj = (j == 0) ? a4.x : (j == 1) ? a4.y : (j == 2) ? a4.z : a4.w;
                float bj = (j == 0) ? b4.x : (j == 1) ? b4.y : (j == 2) ? b4.z : b4.w;
                float4 w1 = *(const float4*)&W1s[k * D + cb];
                float4 w2 = *(const float4*)&W2s[k * D + cb];
                acc0 += aj * w1.x + bj * w2.x;
                acc1 += aj * w1.y + bj * w2.y;
                acc2 += aj * w1.z + bj * w2.z;
                acc3 += aj * w1.w + bj * w2.w;
            }
        }
        int n = n0 + m;
        float4 r;
        r.x = acc0; r.y = acc1; r.z = acc2; r.w = acc3;
        if (act) {
            r.x = r.x >= 0.f ? r.x : NEG_SLOPE * r.x;
            r.y = r.y >= 0.f ? r.y : NEG_SLOPE * r.y;
            r.z = r.z >= 0.f ? r.z : NEG_SLOPE * r.z;
            r.w = r.w >= 0.f ? r.w : NEG_SLOPE * r.w;
        }
        *(float4*)&out[(size_t)n * 192 + cb] = r;
        __syncthreads();
    }
}

extern "C" void kernel_launch(void* const* d_in, const int* in_sizes, int n_in,
                              void* d_out, int out_size, void* d_ws, size_t ws_size,
                              hipStream_t stream) {
    const float* x   = (const float*)d_in[0];
    const float* W1a = (const float*)d_in[1];
    const float* W2a = (const float*)d_in[2];
    const float* W1b = (const float*)d_in[3];
    const float* W2b = (const float*)d_in[4];
    const int*   src = (const int*)d_in[5];
    const int*   dst = (const int*)d_in[6];
    float* out = (float*)d_out;

    // workspace layout (~66 MB)
    int*   btot    = (int*)d_ws;                    // NB pad 256
    int*   bcnt2   = btot + 256;                    // NB pad 256
    int*   bbase   = bcnt2 + 256;                   // NB+1 pad 256
    int*   degi    = bbase + 256;                   // N
    int*   offs    = degi + N_NODES;                // N
    float* rsd     = (float*)(offs + N_NODES);      // N
    int*   csr_src = (int*)(rsd + N_NODES);         // E
    int2*  pairs   = (int2*)(csr_src + N_EDGES);    // E
    float* s       = (float*)(pairs + N_EDGES);     // N*D

    hipMemsetAsync(btot, 0, 512 * sizeof(int), stream);  // btot + bcnt2

    bhist_k<<<NBIN, 256, 0, stream>>>(dst, btot);
    bscan_k<<<1, 256, 0, stream>>>(btot, bbase);
    bucket_k<<<NBIN, 256, 0, stream>>>(src, dst, bbase, bcnt2, pairs);
    fine_k<<<NB, 512, 0, stream>>>(pairs, bbase, degi, offs, rsd, csr_src);

    int ab = (N_NODES + 3) / 4;   // wave per node
    int cbg = N_NODES / 32;       // 3125, exact

    // layer 1: h1 = lrelu(conv(x, W1a, W2a)) -> out cols [0,64)
    agg_k<<<ab, 256, 0, stream>>>(x, 16, rsd, offs, degi, csr_src, s);
    comb_k<<<cbg, 256, 0, stream>>>(x, D, s, W1a, W2a, out + 0, 1);
    // layer 2: h2 = lrelu(conv(h1, W1b, W2b)) -> out cols [64,128)
    agg_k<<<ab, 256, 0, stream>>>(out + 0, 48, rsd, offs, degi, csr_src, s);
    comb_k<<<cbg, 256, 0, stream>>>(out + 0, 192, s, W1b, W2b, out + 64, 1);
    // layer 3: h3 = conv(h2, W1b, W2b) (no act) -> out cols [128,192)
    agg_k<<<ab, 256, 0, stream>>>(out + 64, 48, rsd, offs, degi, csr_src, s);
    comb_k<<<cbg, 256, 0, stream>>>(out + 64, 192, s, W1b, W2b, out + 128, 0);
}

// Round 6
// 613.612 us; speedup vs baseline: 3.6083x; 1.1973x over previous
//
#include <hip/hip_runtime.h>
#include <hip/hip_bf16.h>

#define N_NODES 100000
#define N_EDGES 3200000
#define D 64
#define NEG_SLOPE 0.01f

#define B_SHIFT 9                          // bucket = 512 nodes
#define NB ((N_NODES + 511) >> B_SHIFT)    // 196 buckets
#define T_EDGES 16384                      // edges per binning block
#define NBIN ((N_EDGES + T_EDGES - 1) / T_EDGES)  // 196 binning blocks

__device__ __forceinline__ unsigned short f2bf(float f) {
    __hip_bfloat16 h = __float2bfloat16(f);
    return *reinterpret_cast<unsigned short*>(&h);
}
__device__ __forceinline__ float bflo(unsigned int u) { return __uint_as_float(u << 16); }
__device__ __forceinline__ float bfhi(unsigned int u) { return __uint_as_float(u & 0xffff0000u); }

// ---------------- bucket histogram (196 counters, LDS-accumulated) ----------------
__global__ __launch_bounds__(256) void bhist_k(const int* __restrict__ dst, int* __restrict__ btot) {
    __shared__ int hist[NB];
    int tid = threadIdx.x;
    for (int b = tid; b < NB; b += 256) hist[b] = 0;
    __syncthreads();
    int e0 = blockIdx.x * T_EDGES;
    int e1 = min(e0 + T_EDGES, N_EDGES);
    for (int e = e0 + tid; e < e1; e += 256) atomicAdd(&hist[dst[e] >> B_SHIFT], 1);
    __syncthreads();
    for (int b = tid; b < NB; b += 256) {
        int h = hist[b];
        if (h) atomicAdd(&btot[b], h);
    }
}

// one-block exclusive scan over the 196 bucket totals -> bbase[0..NB]
__global__ __launch_bounds__(256) void bscan_k(const int* __restrict__ btot, int* __restrict__ bbase) {
    __shared__ int wsum[4];
    int t = threadIdx.x;
    int lane = t & 63, w = t >> 6;
    int v = (t < NB) ? btot[t] : 0;
    int incl = v;
    #pragma unroll
    for (int o = 1; o < 64; o <<= 1) {
        int u = __shfl_up(incl, o, 64);
        if (lane >= o) incl += u;
    }
    if (lane == 63) wsum[w] = incl;
    __syncthreads();
    int woff = 0;
    for (int k = 0; k < w; ++k) woff += wsum[k];
    if (t < NB) bbase[t] = woff + incl - v;
    if (t == NB) bbase[NB] = N_EDGES;
}

// ---------------- coarse placement ----------------
__global__ __launch_bounds__(256) void bucket_k(const int* __restrict__ src, const int* __restrict__ dst,
                                                const int* __restrict__ bbase, int* __restrict__ bcnt2,
                                                int2* __restrict__ pairs) {
    __shared__ int hist[NB];
    __shared__ int cnt2[NB];
    __shared__ int baseL[NB];
    int tid = threadIdx.x;
    for (int b = tid; b < NB; b += 256) { hist[b] = 0; cnt2[b] = 0; }
    __syncthreads();
    int e0 = blockIdx.x * T_EDGES;
    int e1 = min(e0 + T_EDGES, N_EDGES);
    for (int e = e0 + tid; e < e1; e += 256) atomicAdd(&hist[dst[e] >> B_SHIFT], 1);
    __syncthreads();
    for (int b = tid; b < NB; b += 256) {
        int h = hist[b];
        int p = h ? atomicAdd(&bcnt2[b], h) : 0;
        baseL[b] = bbase[b] + p;
    }
    __syncthreads();
    for (int e = e0 + tid; e < e1; e += 256) {
        int dv = dst[e];
        int b = dv >> B_SHIFT;
        int p = atomicAdd(&cnt2[b], 1);
        pairs[(size_t)baseL[b] + p] = make_int2(src[e], dv);
    }
}

// ---------------- fine: per-bucket degree count + scan + scatter ----------------
__global__ __launch_bounds__(512) void fine_k(const int2* __restrict__ pairs, const int* __restrict__ bbase,
                                              int* __restrict__ degi, int* __restrict__ offs,
                                              float* __restrict__ rsd, int* __restrict__ csr_src) {
    __shared__ int cnt[512];
    __shared__ int offl[512];
    __shared__ int wsum[8];
    int b = blockIdx.x, t = threadIdx.x;
    int start = bbase[b];
    int end = bbase[b + 1];
    cnt[t] = 0;
    __syncthreads();
    for (int e = start + t; e < end; e += 512) atomicAdd(&cnt[pairs[e].y & 511], 1);
    __syncthreads();
    int d = cnt[t];
    int lane = t & 63, w = t >> 6;
    int incl = d;
    #pragma unroll
    for (int o = 1; o < 64; o <<= 1) {
        int u = __shfl_up(incl, o, 64);
        if (lane >= o) incl += u;
    }
    if (lane == 63) wsum[w] = incl;
    __syncthreads();
    int woff = 0;
    for (int k = 0; k < w; ++k) woff += wsum[k];
    int myoff = start + woff + incl - d;
    offl[t] = myoff;
    int n = (b << B_SHIFT) + t;
    if (n < N_NODES) {
        degi[n] = d;
        offs[n] = myoff;
        rsd[n] = rsqrtf((float)(d > 0 ? d : 1));
    }
    cnt[t] = 0;
    __syncthreads();
    for (int e = start + t; e < end; e += 512) {
        int2 pr = pairs[e];
        int li = pr.y & 511;
        int p = atomicAdd(&cnt[li], 1);
        csr_src[offl[li] + p] = pr.x;
    }
}

// ---------------- convert x -> rsd-prescaled bf16 (packed rows, 128 B) ----------------
__global__ __launch_bounds__(256) void cvt_k(const float* __restrict__ x, const float* __restrict__ rsd,
                                             unsigned short* __restrict__ xb) {
    int i = blockIdx.x * 256 + threadIdx.x;     // one float4 / uint2 quad
    if (i < N_NODES * 16) {
        int node = i >> 4;
        float rn = rsd[node];
        float4 v = ((const float4*)x)[i];
        unsigned int lo = ((unsigned int)f2bf(rn * v.y) << 16) | f2bf(rn * v.x);
        unsigned int hi = ((unsigned int)f2bf(rn * v.w) << 16) | f2bf(rn * v.z);
        ((uint2*)xb)[i] = make_uint2(lo, hi);
    }
}

// ---------------- per-layer: weighted neighbor sum (bf16 gather) ----------------
// wave per node; lane = (edge-slot g in 0..7, feature-oct q in 0..7):
// 8 edges in flight per gather instr, 16 B/lane (8 bf16), xor-shuffle reduce.
// in rows are PRE-SCALED by rsd_j, so s_i = rsd_i * sum(gather).
__global__ __launch_bounds__(256) void agg_k(const unsigned short* __restrict__ xb,
                                             const float* __restrict__ rsd,
                                             const int* __restrict__ offs, const int* __restrict__ degi,
                                             const int* __restrict__ csr_src, float* __restrict__ s) {
    int node = blockIdx.x * 4 + (threadIdx.x >> 6);
    if (node >= N_NODES) return;
    int lane = threadIdx.x & 63;
    int g = lane >> 3;
    int q = lane & 7;
    int start = offs[node];
    int deg = degi[node];
    const uint4* in4 = (const uint4*)xb;        // row = 8 uint4
    float acc0 = 0.f, acc1 = 0.f, acc2 = 0.f, acc3 = 0.f;
    float acc4 = 0.f, acc5 = 0.f, acc6 = 0.f, acc7 = 0.f;
    for (int j = 0; j < deg; j += 8) {
        int e = j + g;
        bool v = e < deg;
        int sj = csr_src[start + (v ? e : 0)];
        float wv = v ? 1.f : 0.f;
        uint4 pk = in4[(size_t)sj * 8 + q];
        acc0 += wv * bflo(pk.x); acc1 += wv * bfhi(pk.x);
        acc2 += wv * bflo(pk.y); acc3 += wv * bfhi(pk.y);
        acc4 += wv * bflo(pk.z); acc5 += wv * bfhi(pk.z);
        acc6 += wv * bflo(pk.w); acc7 += wv * bfhi(pk.w);
    }
    #pragma unroll
    for (int off = 8; off < 64; off <<= 1) {
        acc0 += __shfl_xor(acc0, off, 64); acc1 += __shfl_xor(acc1, off, 64);
        acc2 += __shfl_xor(acc2, off, 64); acc3 += __shfl_xor(acc3, off, 64);
        acc4 += __shfl_xor(acc4, off, 64); acc5 += __shfl_xor(acc5, off, 64);
        acc6 += __shfl_xor(acc6, off, 64); acc7 += __shfl_xor(acc7, off, 64);
    }
    if (g == 0) {
        float rn = rsd[node];
        float4 r0, r1;
        r0.x = rn * acc0; r0.y = rn * acc1; r0.z = rn * acc2; r0.w = rn * acc3;
        r1.x = rn * acc4; r1.y = rn * acc5; r1.z = rn * acc6; r1.w = rn * acc7;
        ((float4*)s)[node * 16 + q * 2]     = r0;
        ((float4*)s)[node * 16 + q * 2 + 1] = r1;
    }
}

// ---------------- per-layer: combine + GEMM (round-1 proven core) ----------------
// out[n, d] = act( (in[n]+s[n]) @ W1 + (s[n]*in[n]) @ W2 ); optional bf16 epilogue
// writes hb[n] = rsd[n]*h[n] (packed rows) for the next layer's aggregation.
__global__ __launch_bounds__(256) void comb_k(const float* __restrict__ in, int stride,
                                              const float* __restrict__ s,
                                              const float* __restrict__ W1, const float* __restrict__ W2,
                                              float* __restrict__ out, int act,
                                              unsigned short* __restrict__ hb, const float* __restrict__ rsd,
                                              int bfout) {
    __shared__ float W1s[D * D];
    __shared__ float W2s[D * D];
    __shared__ float aL[4][4][D];   // [wave][m][k]
    __shared__ float bL[4][4][D];
    int tid = threadIdx.x;
    {
        const float4* w1v = (const float4*)W1;
        const float4* w2v = (const float4*)W2;
        float4* w1s = (float4*)W1s;
        float4* w2s = (float4*)W2s;
        for (int t = tid; t < D * D / 4; t += 256) { w1s[t] = w1v[t]; w2s[t] = w2v[t]; }
    }
    int w = tid >> 6;
    int l = tid & 63;
    int m = l >> 4;
    int cb = (l & 15) * 4;
    __syncthreads();
    for (int it = 0; it < 2; ++it) {
        int n0 = blockIdx.x * 32 + it * 16 + w * 4;
        #pragma unroll
        for (int mm = 0; mm < 4; ++mm) {
            float xv = in[(size_t)(n0 + mm) * stride + l];
            float sp = s[(size_t)(n0 + mm) * D + l];
            aL[w][mm][l] = xv + sp;
            bL[w][mm][l] = sp * xv;
        }
        __syncthreads();
        float acc0 = 0.f, acc1 = 0.f, acc2 = 0.f, acc3 = 0.f;
        const float4* aV = (const float4*)&aL[w][m][0];
        const float4* bV = (const float4*)&bL[w][m][0];
        #pragma unroll
        for (int kk = 0; kk < 16; ++kk) {
            float4 a4 = aV[kk];
            float4 b4 = bV[kk];
            #pragma unroll
            for (int j = 0; j < 4; ++j) {
                int k = kk * 4 + j;
                float aj = (j == 0) ? a4.x : (j == 1) ? a4.y : (j == 2) ? a4.z : a4.w;
                float bj = (j == 0) ? b4.x : (j == 1) ? b4.y : (j == 2) ? b4.z : b4.w;
                float4 w1 = *(const float4*)&W1s[k * D + cb];
                float4 w2 = *(const float4*)&W2s[k * D + cb];
                acc0 += aj * w1.x + bj * w2.x;
                acc1 += aj * w1.y + bj * w2.y;
                acc2 += aj * w1.z + bj * w2.z;
                acc3 += aj * w1.w + bj * w2.w;
            }
        }
        int n = n0 + m;
        float4 r;
        r.x = acc0; r.y = acc1; r.z = acc2; r.w = acc3;
        if (act) {
            r.x = r.x >= 0.f ? r.x : NEG_SLOPE * r.x;
            r.y = r.y >= 0.f ? r.y : NEG_SLOPE * r.y;
            r.z = r.z >= 0.f ? r.z : NEG_SLOPE * r.z;
            r.w = r.w >= 0.f ? r.w : NEG_SLOPE * r.w;
        }
        *(float4*)&out[(size_t)n * 192 + cb] = r;
        if (bfout) {
            float rn = rsd[n];
            unsigned int lo = ((unsigned int)f2bf(rn * r.y) << 16) | f2bf(rn * r.x);
            unsigned int hi = ((unsigned int)f2bf(rn * r.w) << 16) | f2bf(rn * r.z);
            *(uint2*)&hb[(size_t)n * D + cb] = make_uint2(lo, hi);
        }
        __syncthreads();
    }
}

extern "C" void kernel_launch(void* const* d_in, const int* in_sizes, int n_in,
                              void* d_out, int out_size, void* d_ws, size_t ws_size,
                              hipStream_t stream) {
    const float* x   = (const float*)d_in[0];
    const float* W1a = (const float*)d_in[1];
    const float* W2a = (const float*)d_in[2];
    const float* W1b = (const float*)d_in[3];
    const float* W2b = (const float*)d_in[4];
    const int*   src = (const int*)d_in[5];
    const int*   dst = (const int*)d_in[6];
    float* out = (float*)d_out;

    // workspace layout (~65 MB); xb/hb ALIAS pairs (pairs is dead after fine_k)
    int*   btot    = (int*)d_ws;                    // NB pad 256
    int*   bcnt2   = btot + 256;                    // NB pad 256
    int*   bbase   = bcnt2 + 256;                   // NB+1 pad 256
    int*   degi    = bbase + 256;                   // N
    int*   offs    = degi + N_NODES;                // N
    float* rsd     = (float*)(offs + N_NODES);      // N
    int*   csr_src = (int*)(rsd + N_NODES);         // E
    int2*  pairs   = (int2*)(csr_src + N_EDGES);    // E (25.6 MB)
    unsigned short* xb = (unsigned short*)pairs;        // N*64 bf16 (12.8 MB)
    unsigned short* hb = xb + (size_t)N_NODES * D;      // N*64 bf16 (12.8 MB)
    float* s       = (float*)(pairs + N_EDGES);     // N*D

    hipMemsetAsync(btot, 0, 512 * sizeof(int), stream);  // btot + bcnt2

    bhist_k<<<NBIN, 256, 0, stream>>>(dst, btot);
    bscan_k<<<1, 256, 0, stream>>>(btot, bbase);
    bucket_k<<<NBIN, 256, 0, stream>>>(src, dst, bbase, bcnt2, pairs);
    fine_k<<<NB, 512, 0, stream>>>(pairs, bbase, degi, offs, rsd, csr_src);
    cvt_k<<<(N_NODES * 16 + 255) / 256, 256, 0, stream>>>(x, rsd, xb);   // after fine_k: pairs dead, rsd ready

    int ab = (N_NODES + 3) / 4;   // wave per node
    int cbg = N_NODES / 32;       // 3125, exact

    // layer 1: h1 = lrelu(conv(x, W1a, W2a)) -> out cols [0,64), hb = rsd*h1 (bf16)
    agg_k<<<ab, 256, 0, stream>>>(xb, rsd, offs, degi, csr_src, s);
    comb_k<<<cbg, 256, 0, stream>>>(x, D, s, W1a, W2a, out + 0, 1, hb, rsd, 1);
    // layer 2: h2 = lrelu(conv(h1, W1b, W2b)) -> out cols [64,128), hb = rsd*h2 (bf16)
    agg_k<<<ab, 256, 0, stream>>>(hb, rsd, offs, degi, csr_src, s);
    comb_k<<<cbg, 256, 0, stream>>>(out + 0, 192, s, W1b, W2b, out + 64, 1, hb, rsd, 1);
    // layer 3: h3 = conv(h2, W1b, W2b) (no act) -> out cols [128,192)
    agg_k<<<ab, 256, 0, stream>>>(hb, rsd, offs, degi, csr_src, s);
    comb_k<<<cbg, 256, 0, stream>>>(out + 64, 192, s, W1b, W2b, out + 128, 0, hb, rsd, 0);
}